// Round 5
// baseline (257.522 us; speedup 1.0000x reference)
//
#include <hip/hip_runtime.h>

#define B_   8
#define H_   112
#define W_   112
#define HW_  12544
#define C_   128
#define NH_  4
#define HD_  32
#define KK_  49
#define N_   100352
#define SCALE_ 0.17677669529663687f   // 1/sqrt(32)

typedef __attribute__((ext_vector_type(8))) short short8;
typedef __attribute__((ext_vector_type(4))) float floatx4;
typedef __attribute__((ext_vector_type(4))) _Float16 halfx4;

__device__ __forceinline__ unsigned short f2bf(float f) {
  unsigned u = __float_as_uint(f);
  return (unsigned short)((u + 0x7fffu + ((u >> 16) & 1u)) >> 16);
}
__device__ __forceinline__ float bf2f(unsigned short h) {
  return __uint_as_float(((unsigned)h) << 16);
}

// ---------------- K0: weight prep ----------------
// qkv_w (384x128, [oc][c]) and proj_w (128x128, [oc][c]) -> bf16 hi/lo splits.
// Row-major is already MFMA A-fragment order (lane m16 = oc row, k contiguous).
__global__ __launch_bounds__(256) void k_wt(
    const float* __restrict__ qw, const float* __restrict__ pw,
    unsigned short* __restrict__ wh, unsigned short* __restrict__ wl,
    unsigned short* __restrict__ pwh, unsigned short* __restrict__ pwl)
{
  const int idx = blockIdx.x * 256 + threadIdx.x;
  if (idx < 384 * 128) {
    const float v = qw[idx];
    const unsigned short h = f2bf(v);
    wh[idx] = h;
    wl[idx] = f2bf(v - bf2f(h));
  }
  if (idx < 128 * 128) {
    const float v = pw[idx];
    const unsigned short h = f2bf(v);
    pwh[idx] = h;
    pwl[idx] = f2bf(v - bf2f(h));
  }
}

// ---------------- K1: QKV via split-bf16 MFMA + q.k dot + v store ----------
// R5: block = 32 px (was 64), 4 waves; wave w = head w, all 32 px.
// Rationale: the 64-px form was latency-bound at 2 waves/SIMD (arch ~196 regs:
// 100 VGPR + 96 AGPR acc; Occ 17%, MfmaUtil 16%, HBM 10% - nothing busy).
// Halving the tile halves acc to 48 AGPR -> natural arch ~150 -> 3 waves/SIMD
// WITHOUT any launch-bounds cap (keep (256,2), cap 256: zero spill risk).
// Cost: weight L2 re-reads double (~614 MB L2 chip-wide, well under L2 BW).
//
// Falsified alternatives (do not retry):
//   R1: 3-pass split + (256,4) cap -> ~110 MB scratch traffic, 124 us.
//   R2: 3-pass split + (256,3) cap -> still ~100 MB extra traffic, 95 us.
//   Forced reg caps on this kernel always converted latency into spills.
__global__ __launch_bounds__(256, 2) void k_qkv(
    const float* __restrict__ x, const unsigned short* __restrict__ wh,
    const unsigned short* __restrict__ wl, const float* __restrict__ qb,
    _Float16* __restrict__ vbuf, float* __restrict__ dotbuf)
{
  __shared__ __align__(16) unsigned short xh[32 * 136];  // [px][c] bf16-hi
  __shared__ __align__(16) unsigned short xl[32 * 136];  // [px][c] bf16-lo
  const int tid = threadIdx.x;
  const int b   = blockIdx.x / 392;
  const int hw0 = (blockIdx.x % 392) * 32;

  { // stage: thread = (c,c+1) x 4 px; coalesced float4 loads, packed writes
    const float* xb = x + (size_t)b * C_ * HW_ + hw0;
    const int p4 = (tid & 7) * 4;
#pragma unroll
    for (int rep = 0; rep < 2; ++rep) {
      const int c = ((tid >> 3) + rep * 32) * 2;
      const float4 fa = *(const float4*)(xb + (size_t)c * HW_ + p4);
      const float4 fb = *(const float4*)(xb + (size_t)(c + 1) * HW_ + p4);
      const float va[4] = {fa.x, fa.y, fa.z, fa.w};
      const float vb[4] = {fb.x, fb.y, fb.z, fb.w};
#pragma unroll
      for (int i = 0; i < 4; ++i) {
        const unsigned short ha = f2bf(va[i]), hb = f2bf(vb[i]);
        const unsigned short la = f2bf(va[i] - bf2f(ha));
        const unsigned short lb = f2bf(vb[i] - bf2f(hb));
        *(unsigned*)(xh + (p4 + i) * 136 + c) = (unsigned)ha | ((unsigned)hb << 16);
        *(unsigned*)(xl + (p4 + i) * 136 + c) = (unsigned)la | ((unsigned)lb << 16);
      }
    }
  }
  __syncthreads();

  const int w    = __builtin_amdgcn_readfirstlane(tid >> 6);
  const int l    = tid & 63;
  const int m16  = l & 15;
  const int quad = l >> 4;

  int ocbase[6];
#pragma unroll
  for (int g = 0; g < 6; ++g) ocbase[g] = (g >> 1) * 128 + w * 32 + (g & 1) * 16;

  floatx4 acc[6][2];
#pragma unroll
  for (int g = 0; g < 6; ++g)
#pragma unroll
    for (int p = 0; p < 2; ++p) acc[g][p] = (floatx4){0.f, 0.f, 0.f, 0.f};

  for (int ks = 0; ks < 4; ++ks) {
    short8 bh[2], bl[2];
#pragma unroll
    for (int p = 0; p < 2; ++p) {
      const int off = (p * 16 + m16) * 136 + ks * 32 + quad * 8;
      bh[p] = *(const short8*)(xh + off);
      bl[p] = *(const short8*)(xl + off);
    }
#pragma unroll
    for (int g = 0; g < 6; ++g) {
      const size_t woff = (size_t)(ocbase[g] + m16) * C_ + ks * 32 + quad * 8;
      const short8 ah = *(const short8*)(wh + woff);
      const short8 al = *(const short8*)(wl + woff);
#pragma unroll
      for (int p = 0; p < 2; ++p) {
        acc[g][p] = __builtin_amdgcn_mfma_f32_16x16x32_bf16(ah, bh[p], acc[g][p], 0, 0, 0);
        acc[g][p] = __builtin_amdgcn_mfma_f32_16x16x32_bf16(ah, bl[p], acc[g][p], 0, 0, 0);
        acc[g][p] = __builtin_amdgcn_mfma_f32_16x16x32_bf16(al, bh[p], acc[g][p], 0, 0, 0);
      }
    }
  }

  float bias[6][4];
#pragma unroll
  for (int g = 0; g < 6; ++g)
#pragma unroll
    for (int r = 0; r < 4; ++r) bias[g][r] = qb[ocbase[g] + quad * 4 + r];

  const size_t dbase = (size_t)(b * NH_ + w) * HW_ + hw0;

#pragma unroll
  for (int p = 0; p < 2; ++p) {
    float part = 0.f;
#pragma unroll
    for (int t = 0; t < 2; ++t)
#pragma unroll
      for (int r = 0; r < 4; ++r)
        part += (acc[t][p][r] + bias[t][r]) * (acc[2 + t][p][r] + bias[2 + t][r]);
    part += __shfl_xor(part, 16);
    part += __shfl_xor(part, 32);
    if (l < 16) dotbuf[dbase + p * 16 + l] = part * SCALE_;
  }

#pragma unroll
  for (int t = 0; t < 2; ++t) {
#pragma unroll
    for (int p = 0; p < 2; ++p) {
      halfx4 hv;
#pragma unroll
      for (int r = 0; r < 4; ++r) hv[r] = (_Float16)(acc[4 + t][p][r] + bias[4 + t][r]);
      _Float16* vp = vbuf + (dbase + p * 16 + m16) * HD_ + t * 16 + quad * 4;
      *(halfx4*)vp = hv;
    }
  }
}

// ---------------- K2: neighborhood softmax + A*V -> bf16 hi/lo out ---------
// R4 locality structure (measured win, keep):
//  - `at` table fp32 (fp16 table REGRESSED: 6 blk/CU x 62 KB V-window
//    thrashed the 4 MB XCD-L2; fp32 = 51 KB LDS pins 3 blk/CU).
//  - V is fp16: window 31 KB/block; concurrent set 3x32x31KB ~ 3 MB < L2.
//  - XCD-chunked block swizzle: grid 1568 = 8 XCD x 196; 196 = 4 whole
//    (head,b) groups of 49 tiles -> each group's entire V (0.8 MB) stays in
//    one XCD's L2; window overlap becomes L2 hits.
__global__ __launch_bounds__(256) void k_attn(
    const _Float16* __restrict__ vbuf, const float* __restrict__ dotbuf,
    const float* __restrict__ rpb, unsigned short* __restrict__ ao_h,
    unsigned short* __restrict__ ao_l)
{
  __shared__ __align__(16) float at[KK_ * 256];
  __shared__ float rsum[256];
  const int tid  = threadIdx.x;
  const int blk  = ((int)blockIdx.x & 7) * 196 + ((int)blockIdx.x >> 3);
  const int head = blk / 392;
  const int rem  = blk % 392;
  const int b    = rem / 49;
  const int t49  = rem % 49;
  const int r0 = (t49 / 7) * 16;
  const int w0 = (t49 % 7) * 16;
  const float* dptr = dotbuf + (size_t)(b * NH_ + head) * HW_;

  {
    const int r = tid >> 4, wv = tid & 15;
    const int gh = r0 + r, gw = w0 + wv;
    float logit[KK_];
    float m = -1e30f;
#pragma unroll
    for (int i = 0; i < 7; ++i) {
      int hr = gh + i; if (hr >= H_) hr -= H_;
      const float* drow = dptr + hr * W_;
#pragma unroll
      for (int j = 0; j < 7; ++j) {
        int wc = gw + j; if (wc >= W_) wc -= W_;
        const float l = drow[wc] + rpb[head * KK_ + i * 7 + j];
        logit[i * 7 + j] = l;
        m = fmaxf(m, l);
      }
    }
    float s = 0.f;
#pragma unroll
    for (int o = 0; o < KK_; ++o) {
      const float e = __expf(logit[o] - m);
      s += e;
      at[o * 256 + tid] = e;
    }
    rsum[tid] = 1.0f / s;
  }
  __syncthreads();

  const int c4  = tid & 7;
  const int seg = tid >> 3;
  const int r   = seg >> 1;
  const int sx  = (seg & 1) * 8;
  const int gh  = r0 + r;
  const int pxb = r * 16 + sx;
  const _Float16* vb = vbuf + (size_t)(b * NH_ + head) * HW_ * HD_ + c4 * 4;

  float4 acc[8];
#pragma unroll
  for (int xx = 0; xx < 8; ++xx) acc[xx] = make_float4(0.f, 0.f, 0.f, 0.f);

  for (int i = 0; i < 7; ++i) {
    int hr = gh + i; if (hr >= H_) hr -= H_;
    float4 win[14];
#pragma unroll
    for (int t = 0; t < 14; ++t) {
      int wc = w0 + sx + t; if (wc >= W_) wc -= W_;
      const halfx4 hv = *(const halfx4*)(vb + ((size_t)hr * W_ + wc) * HD_);
      win[t] = make_float4((float)hv[0], (float)hv[1], (float)hv[2], (float)hv[3]);
    }
#pragma unroll
    for (int j = 0; j < 7; ++j) {
      const float* arow = at + (i * 7 + j) * 256 + pxb;
      const float4 a0 = *(const float4*)arow;
      const float4 a1 = *(const float4*)(arow + 4);
      const float aw[8] = {a0.x, a0.y, a0.z, a0.w, a1.x, a1.y, a1.z, a1.w};
#pragma unroll
      for (int xx = 0; xx < 8; ++xx) {
        acc[xx].x = fmaf(aw[xx], win[xx + j].x, acc[xx].x);
        acc[xx].y = fmaf(aw[xx], win[xx + j].y, acc[xx].y);
        acc[xx].z = fmaf(aw[xx], win[xx + j].z, acc[xx].z);
        acc[xx].w = fmaf(aw[xx], win[xx + j].w, acc[xx].w);
      }
    }
  }

  // out: (B,HW,C) bf16 hi/lo planes, c = head*32 + c4*4 .. +3 (8B aligned)
  const size_t obase =
      ((size_t)b * HW_ + (size_t)gh * W_ + (w0 + sx)) * C_ + head * HD_ + c4 * 4;
#pragma unroll
  for (int xx = 0; xx < 8; ++xx) {
    const float rs = rsum[pxb + xx];
    const float o0 = acc[xx].x * rs, o1 = acc[xx].y * rs;
    const float o2 = acc[xx].z * rs, o3 = acc[xx].w * rs;
    const unsigned short h0 = f2bf(o0), h1 = f2bf(o1), h2 = f2bf(o2), h3 = f2bf(o3);
    ushort4 hv; hv.x = h0; hv.y = h1; hv.z = h2; hv.w = h3;
    ushort4 lv;
    lv.x = f2bf(o0 - bf2f(h0)); lv.y = f2bf(o1 - bf2f(h1));
    lv.z = f2bf(o2 - bf2f(h2)); lv.w = f2bf(o3 - bf2f(h3));
    *(ushort4*)(ao_h + obase + (size_t)xx * C_) = hv;
    *(ushort4*)(ao_l + obase + (size_t)xx * C_) = lv;
  }
}

// ---------------- K3: proj via split-bf16 MFMA + NHWC -> NCHW --------------
// Block = 64 px, 4 waves; wave w -> oc in [w*32, w*32+32). No LDS, no barrier.
// (256,2): R1's (256,4) bump was measured ~neutral.
__global__ __launch_bounds__(256, 2) void k_proj(
    const unsigned short* __restrict__ ao_h, const unsigned short* __restrict__ ao_l,
    const unsigned short* __restrict__ pwh, const unsigned short* __restrict__ pwl,
    const float* __restrict__ pb, float* __restrict__ out)
{
  const int tid = threadIdx.x;
  const int b   = blockIdx.x / 196;
  const int hw0 = (blockIdx.x % 196) * 64;
  const int w    = __builtin_amdgcn_readfirstlane(tid >> 6);
  const int l    = tid & 63;
  const int m16  = l & 15;
  const int quad = l >> 4;

  floatx4 acc[2][4];
#pragma unroll
  for (int t = 0; t < 2; ++t)
#pragma unroll
    for (int p = 0; p < 4; ++p) acc[t][p] = (floatx4){0.f, 0.f, 0.f, 0.f};

  const size_t pxbase = (size_t)b * HW_ + hw0;

  for (int ks = 0; ks < 4; ++ks) {
    short8 bh[4], bl[4];
#pragma unroll
    for (int p = 0; p < 4; ++p) {
      const size_t off = (pxbase + p * 16 + m16) * C_ + ks * 32 + quad * 8;
      bh[p] = *(const short8*)(ao_h + off);
      bl[p] = *(const short8*)(ao_l + off);
    }
#pragma unroll
    for (int t = 0; t < 2; ++t) {
      const size_t woff = (size_t)(w * 32 + t * 16 + m16) * C_ + ks * 32 + quad * 8;
      const short8 wah = *(const short8*)(pwh + woff);
      const short8 wal = *(const short8*)(pwl + woff);
#pragma unroll
      for (int p = 0; p < 4; ++p) {
        acc[t][p] = __builtin_amdgcn_mfma_f32_16x16x32_bf16(wah, bh[p], acc[t][p], 0, 0, 0);
        acc[t][p] = __builtin_amdgcn_mfma_f32_16x16x32_bf16(wah, bl[p], acc[t][p], 0, 0, 0);
        acc[t][p] = __builtin_amdgcn_mfma_f32_16x16x32_bf16(wal, bh[p], acc[t][p], 0, 0, 0);
      }
    }
  }

#pragma unroll
  for (int t = 0; t < 2; ++t) {
    float bias[4];
#pragma unroll
    for (int r = 0; r < 4; ++r) bias[r] = pb[w * 32 + t * 16 + quad * 4 + r];
#pragma unroll
    for (int p = 0; p < 4; ++p) {
#pragma unroll
      for (int r = 0; r < 4; ++r) {
        const int oc = w * 32 + t * 16 + quad * 4 + r;
        out[(size_t)b * C_ * HW_ + (size_t)oc * HW_ + hw0 + p * 16 + m16] =
            acc[t][p][r] + bias[r];
      }
    }
  }
}

extern "C" void kernel_launch(void* const* d_in, const int* in_sizes, int n_in,
                              void* d_out, int out_size, void* d_ws, size_t ws_size,
                              hipStream_t stream) {
  const float* x   = (const float*)d_in[0];
  const float* qw  = (const float*)d_in[1];
  const float* qb  = (const float*)d_in[2];
  const float* rpb = (const float*)d_in[3];
  const float* pw  = (const float*)d_in[4];
  const float* pb  = (const float*)d_in[5];
  float* out = (float*)d_out;

  _Float16* vbuf = (_Float16*)d_ws;                    // N*C fp16 (25.7 MB)
  float* dotb = (float*)(vbuf + (size_t)N_ * C_);      // N*NH fp32 (1.6 MB)
  unsigned short* ao_h = (unsigned short*)(dotb + (size_t)N_ * NH_);  // N*C bf16
  unsigned short* ao_l = ao_h + (size_t)N_ * C_;       // N*C bf16
  unsigned short* wh   = ao_l + (size_t)N_ * C_;       // 384*128 bf16
  unsigned short* wl   = wh + 384 * C_;
  unsigned short* pwh  = wl + 384 * C_;                // 128*128 bf16
  unsigned short* pwl  = pwh + C_ * C_;

  hipLaunchKernelGGL(k_wt,   dim3(192), dim3(256), 0, stream, qw, pw, wh, wl, pwh, pwl);
  hipLaunchKernelGGL(k_qkv,  dim3(N_ / 32), dim3(256), 0, stream, x, wh, wl, qb, vbuf, dotb);
  hipLaunchKernelGGL(k_attn, dim3(NH_ * B_ * 49), dim3(256), 0, stream, vbuf, dotb, rpb, ao_h, ao_l);
  hipLaunchKernelGGL(k_proj, dim3(N_ / 64), dim3(256), 0, stream, ao_h, ao_l, pwh, pwl, pb, out);
}

// Round 6
// 207.703 us; speedup vs baseline: 1.2399x; 1.2399x over previous
//
#include <hip/hip_runtime.h>

#define B_   8
#define H_   112
#define W_   112
#define HW_  12544
#define C_   128
#define NH_  4
#define HD_  32
#define KK_  49
#define N_   100352
#define SCALE_ 0.17677669529663687f   // 1/sqrt(32)

typedef __attribute__((ext_vector_type(8))) short short8;
typedef __attribute__((ext_vector_type(4))) float floatx4;
typedef __attribute__((ext_vector_type(4))) _Float16 halfx4;
typedef __attribute__((ext_vector_type(8))) _Float16 half8;

__device__ __forceinline__ unsigned short f2bf(float f) {
  unsigned u = __float_as_uint(f);
  return (unsigned short)((u + 0x7fffu + ((u >> 16) & 1u)) >> 16);
}
__device__ __forceinline__ float bf2f(unsigned short h) {
  return __uint_as_float(((unsigned)h) << 16);
}

// ---------------- K0: weight prep ----------------
// qkv_w (384x128) -> bf16 hi/lo split (k_qkv needs split precision: x~N(0,1)).
// proj_w (128x128) -> single fp16 plane (R6: ao path is fp16; w~0.02, fp16
// rel err 2^-11 is negligible through the proj dot).
__global__ __launch_bounds__(256) void k_wt(
    const float* __restrict__ qw, const float* __restrict__ pw,
    unsigned short* __restrict__ wh, unsigned short* __restrict__ wl,
    _Float16* __restrict__ pwf)
{
  const int idx = blockIdx.x * 256 + threadIdx.x;
  if (idx < 384 * 128) {
    const float v = qw[idx];
    const unsigned short h = f2bf(v);
    wh[idx] = h;
    wl[idx] = f2bf(v - bf2f(h));
  }
  if (idx < 128 * 128) {
    pwf[idx] = (_Float16)pw[idx];
  }
}

// ---------------- K1: QKV via split-bf16 MFMA + q.k dot + v store ----------
// Block = 64 px, 4 waves; wave w = head w. LDS 34.8 KB.
// R4 form — measured 67 us, FETCH 26 / WRITE 26.7 MB clean. PINNED.
// Falsified alternatives (do not retry):
//   R1: 3-pass split + (256,4) cap -> spills (~110 MB scratch), 124 us.
//   R2: 3-pass split + (256,3) cap -> still spills, 95 us.
//   R5: 32-px tile -> Occ 39% but MFMA:weight-load ratio halves -> 100 us.
__global__ __launch_bounds__(256, 2) void k_qkv(
    const float* __restrict__ x, const unsigned short* __restrict__ wh,
    const unsigned short* __restrict__ wl, const float* __restrict__ qb,
    _Float16* __restrict__ vbuf, float* __restrict__ dotbuf)
{
  __shared__ __align__(16) unsigned short xh[64 * 136];  // [px][c] bf16-hi
  __shared__ __align__(16) unsigned short xl[64 * 136];  // [px][c] bf16-lo
  const int tid = threadIdx.x;
  const int b   = blockIdx.x / 196;
  const int hw0 = (blockIdx.x % 196) * 64;

  { // stage: thread = (c,c+1) x 4 px; coalesced float4 loads, packed writes
    const float* xb = x + (size_t)b * C_ * HW_ + hw0;
    const int p4 = (tid & 15) * 4;
#pragma unroll
    for (int rep = 0; rep < 4; ++rep) {
      const int c = ((tid >> 4) + rep * 16) * 2;
      const float4 fa = *(const float4*)(xb + (size_t)c * HW_ + p4);
      const float4 fb = *(const float4*)(xb + (size_t)(c + 1) * HW_ + p4);
      const float va[4] = {fa.x, fa.y, fa.z, fa.w};
      const float vb[4] = {fb.x, fb.y, fb.z, fb.w};
#pragma unroll
      for (int i = 0; i < 4; ++i) {
        const unsigned short ha = f2bf(va[i]), hb = f2bf(vb[i]);
        const unsigned short la = f2bf(va[i] - bf2f(ha));
        const unsigned short lb = f2bf(vb[i] - bf2f(hb));
        *(unsigned*)(xh + (p4 + i) * 136 + c) = (unsigned)ha | ((unsigned)hb << 16);
        *(unsigned*)(xl + (p4 + i) * 136 + c) = (unsigned)la | ((unsigned)lb << 16);
      }
    }
  }
  __syncthreads();

  const int w    = __builtin_amdgcn_readfirstlane(tid >> 6);
  const int l    = tid & 63;
  const int m16  = l & 15;
  const int quad = l >> 4;

  int ocbase[6];
#pragma unroll
  for (int g = 0; g < 6; ++g) ocbase[g] = (g >> 1) * 128 + w * 32 + (g & 1) * 16;

  floatx4 acc[6][4];
#pragma unroll
  for (int g = 0; g < 6; ++g)
#pragma unroll
    for (int p = 0; p < 4; ++p) acc[g][p] = (floatx4){0.f, 0.f, 0.f, 0.f};

  for (int ks = 0; ks < 4; ++ks) {
    short8 bh[4], bl[4];
#pragma unroll
    for (int p = 0; p < 4; ++p) {
      const int off = (p * 16 + m16) * 136 + ks * 32 + quad * 8;
      bh[p] = *(const short8*)(xh + off);
      bl[p] = *(const short8*)(xl + off);
    }
#pragma unroll
    for (int g = 0; g < 6; ++g) {
      const size_t woff = (size_t)(ocbase[g] + m16) * C_ + ks * 32 + quad * 8;
      const short8 ah = *(const short8*)(wh + woff);
      const short8 al = *(const short8*)(wl + woff);
#pragma unroll
      for (int p = 0; p < 4; ++p) {
        acc[g][p] = __builtin_amdgcn_mfma_f32_16x16x32_bf16(ah, bh[p], acc[g][p], 0, 0, 0);
        acc[g][p] = __builtin_amdgcn_mfma_f32_16x16x32_bf16(ah, bl[p], acc[g][p], 0, 0, 0);
        acc[g][p] = __builtin_amdgcn_mfma_f32_16x16x32_bf16(al, bh[p], acc[g][p], 0, 0, 0);
      }
    }
  }

  float bias[6][4];
#pragma unroll
  for (int g = 0; g < 6; ++g)
#pragma unroll
    for (int r = 0; r < 4; ++r) bias[g][r] = qb[ocbase[g] + quad * 4 + r];

  const size_t dbase = (size_t)(b * NH_ + w) * HW_ + hw0;

#pragma unroll
  for (int p = 0; p < 4; ++p) {
    float part = 0.f;
#pragma unroll
    for (int t = 0; t < 2; ++t)
#pragma unroll
      for (int r = 0; r < 4; ++r)
        part += (acc[t][p][r] + bias[t][r]) * (acc[2 + t][p][r] + bias[2 + t][r]);
    part += __shfl_xor(part, 16);
    part += __shfl_xor(part, 32);
    if (l < 16) dotbuf[dbase + p * 16 + l] = part * SCALE_;
  }

#pragma unroll
  for (int t = 0; t < 2; ++t) {
#pragma unroll
    for (int p = 0; p < 4; ++p) {
      halfx4 hv;
#pragma unroll
      for (int r = 0; r < 4; ++r) hv[r] = (_Float16)(acc[4 + t][p][r] + bias[4 + t][r]);
      _Float16* vp = vbuf + (dbase + p * 16 + m16) * HD_ + t * 16 + quad * 4;
      *(halfx4*)vp = hv;
    }
  }
}

// ---------------- K2: neighborhood softmax + A*V -> fp16 out --------------
// R4 locality structure (measured win, keep):
//  - `at` table fp32 (fp16 table REGRESSED: 6 blk/CU x 62 KB V-window
//    thrashed the 4 MB XCD-L2; fp32 = 51 KB LDS pins 3 blk/CU).
//  - V is fp16: window 31 KB/block; concurrent set 3x32x31KB ~ 3 MB < L2.
//  - XCD-chunked block swizzle: grid 1568 = 8 XCD x 196; 196 = 4 whole
//    (head,b) groups of 49 tiles -> each group's entire V (0.8 MB) stays in
//    one XCD's L2; window overlap becomes L2 hits.
// R6: ao output single fp16 plane (was bf16 hi/lo): write 52 -> 26 MB and
// no lo-residual math. fp16 err (~1.1e-4 abs on ~0.23 values) propagates to
// ~5e-5 on the final output — under the passing 2.44e-4 budget.
__global__ __launch_bounds__(256) void k_attn(
    const _Float16* __restrict__ vbuf, const float* __restrict__ dotbuf,
    const float* __restrict__ rpb, _Float16* __restrict__ aof)
{
  __shared__ __align__(16) float at[KK_ * 256];
  __shared__ float rsum[256];
  const int tid  = threadIdx.x;
  const int blk  = ((int)blockIdx.x & 7) * 196 + ((int)blockIdx.x >> 3);
  const int head = blk / 392;
  const int rem  = blk % 392;
  const int b    = rem / 49;
  const int t49  = rem % 49;
  const int r0 = (t49 / 7) * 16;
  const int w0 = (t49 % 7) * 16;
  const float* dptr = dotbuf + (size_t)(b * NH_ + head) * HW_;

  {
    const int r = tid >> 4, wv = tid & 15;
    const int gh = r0 + r, gw = w0 + wv;
    float logit[KK_];
    float m = -1e30f;
#pragma unroll
    for (int i = 0; i < 7; ++i) {
      int hr = gh + i; if (hr >= H_) hr -= H_;
      const float* drow = dptr + hr * W_;
#pragma unroll
      for (int j = 0; j < 7; ++j) {
        int wc = gw + j; if (wc >= W_) wc -= W_;
        const float l = drow[wc] + rpb[head * KK_ + i * 7 + j];
        logit[i * 7 + j] = l;
        m = fmaxf(m, l);
      }
    }
    float s = 0.f;
#pragma unroll
    for (int o = 0; o < KK_; ++o) {
      const float e = __expf(logit[o] - m);
      s += e;
      at[o * 256 + tid] = e;
    }
    rsum[tid] = 1.0f / s;
  }
  __syncthreads();

  const int c4  = tid & 7;
  const int seg = tid >> 3;
  const int r   = seg >> 1;
  const int sx  = (seg & 1) * 8;
  const int gh  = r0 + r;
  const int pxb = r * 16 + sx;
  const _Float16* vb = vbuf + (size_t)(b * NH_ + head) * HW_ * HD_ + c4 * 4;

  float4 acc[8];
#pragma unroll
  for (int xx = 0; xx < 8; ++xx) acc[xx] = make_float4(0.f, 0.f, 0.f, 0.f);

  for (int i = 0; i < 7; ++i) {
    int hr = gh + i; if (hr >= H_) hr -= H_;
    float4 win[14];
#pragma unroll
    for (int t = 0; t < 14; ++t) {
      int wc = w0 + sx + t; if (wc >= W_) wc -= W_;
      const halfx4 hv = *(const halfx4*)(vb + ((size_t)hr * W_ + wc) * HD_);
      win[t] = make_float4((float)hv[0], (float)hv[1], (float)hv[2], (float)hv[3]);
    }
#pragma unroll
    for (int j = 0; j < 7; ++j) {
      const float* arow = at + (i * 7 + j) * 256 + pxb;
      const float4 a0 = *(const float4*)arow;
      const float4 a1 = *(const float4*)(arow + 4);
      const float aw[8] = {a0.x, a0.y, a0.z, a0.w, a1.x, a1.y, a1.z, a1.w};
#pragma unroll
      for (int xx = 0; xx < 8; ++xx) {
        acc[xx].x = fmaf(aw[xx], win[xx + j].x, acc[xx].x);
        acc[xx].y = fmaf(aw[xx], win[xx + j].y, acc[xx].y);
        acc[xx].z = fmaf(aw[xx], win[xx + j].z, acc[xx].z);
        acc[xx].w = fmaf(aw[xx], win[xx + j].w, acc[xx].w);
      }
    }
  }

  // out: (B,HW,C) fp16, c = head*32 + c4*4 .. +3 (8B aligned)
  const size_t obase =
      ((size_t)b * HW_ + (size_t)gh * W_ + (w0 + sx)) * C_ + head * HD_ + c4 * 4;
#pragma unroll
  for (int xx = 0; xx < 8; ++xx) {
    const float rs = rsum[pxb + xx];
    halfx4 hv;
    hv[0] = (_Float16)(acc[xx].x * rs);
    hv[1] = (_Float16)(acc[xx].y * rs);
    hv[2] = (_Float16)(acc[xx].z * rs);
    hv[3] = (_Float16)(acc[xx].w * rs);
    *(halfx4*)(aof + obase + (size_t)xx * C_) = hv;
  }
}

// ---------------- K3: proj via fp16 MFMA + NHWC -> NCHW -------------------
// Block = 64 px, 4 waves; wave w -> oc in [w*32, w*32+32). No LDS, no barrier.
// R6: single fp16 ao plane + fp16 weights + mfma_f32_16x16x32_f16:
// 3x fewer MFMAs, 2x fewer loads vs the bf16 hi/lo split.
__global__ __launch_bounds__(256, 2) void k_proj(
    const _Float16* __restrict__ aof, const _Float16* __restrict__ pwf,
    const float* __restrict__ pb, float* __restrict__ out)
{
  const int tid = threadIdx.x;
  const int b   = blockIdx.x / 196;
  const int hw0 = (blockIdx.x % 196) * 64;
  const int w    = __builtin_amdgcn_readfirstlane(tid >> 6);
  const int l    = tid & 63;
  const int m16  = l & 15;
  const int quad = l >> 4;

  floatx4 acc[2][4];
#pragma unroll
  for (int t = 0; t < 2; ++t)
#pragma unroll
    for (int p = 0; p < 4; ++p) acc[t][p] = (floatx4){0.f, 0.f, 0.f, 0.f};

  const size_t pxbase = (size_t)b * HW_ + hw0;

  for (int ks = 0; ks < 4; ++ks) {
    half8 bb[4];
#pragma unroll
    for (int p = 0; p < 4; ++p) {
      const size_t off = (pxbase + p * 16 + m16) * C_ + ks * 32 + quad * 8;
      bb[p] = *(const half8*)(aof + off);
    }
#pragma unroll
    for (int t = 0; t < 2; ++t) {
      const size_t woff = (size_t)(w * 32 + t * 16 + m16) * C_ + ks * 32 + quad * 8;
      const half8 wa = *(const half8*)(pwf + woff);
#pragma unroll
      for (int p = 0; p < 4; ++p) {
        acc[t][p] = __builtin_amdgcn_mfma_f32_16x16x32_f16(wa, bb[p], acc[t][p], 0, 0, 0);
      }
    }
  }

#pragma unroll
  for (int t = 0; t < 2; ++t) {
    float bias[4];
#pragma unroll
    for (int r = 0; r < 4; ++r) bias[r] = pb[w * 32 + t * 16 + quad * 4 + r];
#pragma unroll
    for (int p = 0; p < 4; ++p) {
#pragma unroll
      for (int r = 0; r < 4; ++r) {
        const int oc = w * 32 + t * 16 + quad * 4 + r;
        out[(size_t)b * C_ * HW_ + (size_t)oc * HW_ + hw0 + p * 16 + m16] =
            acc[t][p][r] + bias[r];
      }
    }
  }
}

extern "C" void kernel_launch(void* const* d_in, const int* in_sizes, int n_in,
                              void* d_out, int out_size, void* d_ws, size_t ws_size,
                              hipStream_t stream) {
  const float* x   = (const float*)d_in[0];
  const float* qw  = (const float*)d_in[1];
  const float* qb  = (const float*)d_in[2];
  const float* rpb = (const float*)d_in[3];
  const float* pw  = (const float*)d_in[4];
  const float* pb  = (const float*)d_in[5];
  float* out = (float*)d_out;

  _Float16* vbuf = (_Float16*)d_ws;                    // N*C fp16 (25.7 MB)
  float* dotb = (float*)(vbuf + (size_t)N_ * C_);      // N*NH fp32 (1.6 MB)
  _Float16* aof = (_Float16*)(dotb + (size_t)N_ * NH_); // N*C fp16 (25.7 MB)
  unsigned short* wh = (unsigned short*)(aof + (size_t)N_ * C_);  // 384*128 bf16
  unsigned short* wl = wh + 384 * C_;
  _Float16* pwf = (_Float16*)(wl + 384 * C_);          // 128*128 fp16

  hipLaunchKernelGGL(k_wt,   dim3(192), dim3(256), 0, stream, qw, pw, wh, wl, pwf);
  hipLaunchKernelGGL(k_qkv,  dim3(N_ / 64), dim3(256), 0, stream, x, wh, wl, qb, vbuf, dotb);
  hipLaunchKernelGGL(k_attn, dim3(NH_ * B_ * 49), dim3(256), 0, stream, vbuf, dotb, rpb, aof);
  hipLaunchKernelGGL(k_proj, dim3(N_ / 64), dim3(256), 0, stream, aof, pwf, pb, out);
}

// Round 7
// 185.723 us; speedup vs baseline: 1.3866x; 1.1183x over previous
//
#include <hip/hip_runtime.h>

#define B_   8
#define H_   112
#define W_   112
#define HW_  12544
#define C_   128
#define NH_  4
#define HD_  32
#define KK_  49
#define N_   100352
#define SCALE_ 0.17677669529663687f   // 1/sqrt(32)

typedef __attribute__((ext_vector_type(4))) float floatx4;
typedef __attribute__((ext_vector_type(4))) _Float16 halfx4;
typedef __attribute__((ext_vector_type(8))) _Float16 half8;

// ---------------- K0: weight prep ----------------
// R7: both weight matrices -> single fp16 plane. Error analysis: logits are
// tiny (|q.k|*scale ~ 0.05, softmax near-uniform) so q/k rounding at fp16
// u=2^-11 perturbs the output ~1e-5; v-path adds ~3e-5 after proj. The old
// bf16 hi/lo split (u~2^-16, 3 MFMAs) was over-provisioned.
__global__ __launch_bounds__(256) void k_wt(
    const float* __restrict__ qw, const float* __restrict__ pw,
    _Float16* __restrict__ qwf, _Float16* __restrict__ pwf)
{
  const int idx = blockIdx.x * 256 + threadIdx.x;
  if (idx < 384 * 128) qwf[idx] = (_Float16)qw[idx];
  if (idx < 128 * 128) pwf[idx] = (_Float16)pw[idx];
}

// ---------------- K1: QKV via fp16 MFMA + q.k dot + v store ----------------
// Block = 64 px, 4 waves; wave w = head w. LDS 17.4 KB (fp16 x plane).
// R7: single fp16 plane (was bf16 hi/lo x3 MFMA): MFMA/3, weight loads /2,
// and ~30 VGPRs freed (B-frags 32->16, one A-frag) -> natural allocation
// ~160 <= 170 -> 3 waves/SIMD organically. (256,2) is only a CAP (no spill
// risk); occupancy follows actual allocation.
// Falsified alternatives (do not retry):
//   R1: 3-pass split + (256,4) cap -> spills (~110 MB scratch), 124 us.
//   R2: 3-pass split + (256,3) cap -> still spills, 95 us.
//   R5: 32-px tile -> Occ 39% but MFMA:weight-load ratio halves -> 100 us.
__global__ __launch_bounds__(256, 2) void k_qkv(
    const float* __restrict__ x, const _Float16* __restrict__ qwf,
    const float* __restrict__ qb,
    _Float16* __restrict__ vbuf, float* __restrict__ dotbuf)
{
  __shared__ __align__(16) _Float16 xf[64 * 136];  // [px][c] fp16
  const int tid = threadIdx.x;
  const int b   = blockIdx.x / 196;
  const int hw0 = (blockIdx.x % 196) * 64;

  { // stage: thread = (c,c+1) x 4 px; coalesced float4 loads, packed writes
    const float* xb = x + (size_t)b * C_ * HW_ + hw0;
    const int p4 = (tid & 15) * 4;
#pragma unroll
    for (int rep = 0; rep < 4; ++rep) {
      const int c = ((tid >> 4) + rep * 16) * 2;
      const float4 fa = *(const float4*)(xb + (size_t)c * HW_ + p4);
      const float4 fb = *(const float4*)(xb + (size_t)(c + 1) * HW_ + p4);
      const float va[4] = {fa.x, fa.y, fa.z, fa.w};
      const float vb[4] = {fb.x, fb.y, fb.z, fb.w};
#pragma unroll
      for (int i = 0; i < 4; ++i) {
        union { _Float16 h[2]; unsigned u; } pk;
        pk.h[0] = (_Float16)va[i];
        pk.h[1] = (_Float16)vb[i];
        *(unsigned*)(xf + (p4 + i) * 136 + c) = pk.u;
      }
    }
  }
  __syncthreads();

  const int w    = __builtin_amdgcn_readfirstlane(tid >> 6);
  const int l    = tid & 63;
  const int m16  = l & 15;
  const int quad = l >> 4;

  int ocbase[6];
#pragma unroll
  for (int g = 0; g < 6; ++g) ocbase[g] = (g >> 1) * 128 + w * 32 + (g & 1) * 16;

  floatx4 acc[6][4];
#pragma unroll
  for (int g = 0; g < 6; ++g)
#pragma unroll
    for (int p = 0; p < 4; ++p) acc[g][p] = (floatx4){0.f, 0.f, 0.f, 0.f};

  for (int ks = 0; ks < 4; ++ks) {
    half8 bb[4];
#pragma unroll
    for (int p = 0; p < 4; ++p) {
      const int off = (p * 16 + m16) * 136 + ks * 32 + quad * 8;
      bb[p] = *(const half8*)(xf + off);
    }
#pragma unroll
    for (int g = 0; g < 6; ++g) {
      const size_t woff = (size_t)(ocbase[g] + m16) * C_ + ks * 32 + quad * 8;
      const half8 wa = *(const half8*)(qwf + woff);
#pragma unroll
      for (int p = 0; p < 4; ++p) {
        acc[g][p] = __builtin_amdgcn_mfma_f32_16x16x32_f16(wa, bb[p], acc[g][p], 0, 0, 0);
      }
    }
  }

  float bias[6][4];
#pragma unroll
  for (int g = 0; g < 6; ++g)
#pragma unroll
    for (int r = 0; r < 4; ++r) bias[g][r] = qb[ocbase[g] + quad * 4 + r];

  const size_t dbase = (size_t)(b * NH_ + w) * HW_ + hw0;

#pragma unroll
  for (int p = 0; p < 4; ++p) {
    float part = 0.f;
#pragma unroll
    for (int t = 0; t < 2; ++t)
#pragma unroll
      for (int r = 0; r < 4; ++r)
        part += (acc[t][p][r] + bias[t][r]) * (acc[2 + t][p][r] + bias[2 + t][r]);
    part += __shfl_xor(part, 16);
    part += __shfl_xor(part, 32);
    if (l < 16) dotbuf[dbase + p * 16 + l] = part * SCALE_;
  }

#pragma unroll
  for (int t = 0; t < 2; ++t) {
#pragma unroll
    for (int p = 0; p < 4; ++p) {
      halfx4 hv;
#pragma unroll
      for (int r = 0; r < 4; ++r) hv[r] = (_Float16)(acc[4 + t][p][r] + bias[4 + t][r]);
      _Float16* vp = vbuf + (dbase + p * 16 + m16) * HD_ + t * 16 + quad * 4;
      *(halfx4*)vp = hv;
    }
  }
}

// ---------------- K2: neighborhood softmax + A*V -> fp16 out --------------
// R4 locality structure (measured win, keep):
//  - `at` table fp32 (fp16 table REGRESSED: 6 blk/CU x 62 KB V-window
//    thrashed the 4 MB XCD-L2; fp32 = 51 KB LDS pins 3 blk/CU).
//  - V is fp16: window 31 KB/block; concurrent set 3x32x31KB ~ 3 MB < L2.
//  - XCD-chunked block swizzle: grid 1568 = 8 XCD x 196; 196 = 4 whole
//    (head,b) groups of 49 tiles -> each group's entire V (0.8 MB) stays in
//    one XCD's L2; window overlap becomes L2 hits.
// R6: ao output single fp16 plane (write 52 -> 26 MB) — measured win, keep.
__global__ __launch_bounds__(256) void k_attn(
    const _Float16* __restrict__ vbuf, const float* __restrict__ dotbuf,
    const float* __restrict__ rpb, _Float16* __restrict__ aof)
{
  __shared__ __align__(16) float at[KK_ * 256];
  __shared__ float rsum[256];
  const int tid  = threadIdx.x;
  const int blk  = ((int)blockIdx.x & 7) * 196 + ((int)blockIdx.x >> 3);
  const int head = blk / 392;
  const int rem  = blk % 392;
  const int b    = rem / 49;
  const int t49  = rem % 49;
  const int r0 = (t49 / 7) * 16;
  const int w0 = (t49 % 7) * 16;
  const float* dptr = dotbuf + (size_t)(b * NH_ + head) * HW_;

  {
    const int r = tid >> 4, wv = tid & 15;
    const int gh = r0 + r, gw = w0 + wv;
    float logit[KK_];
    float m = -1e30f;
#pragma unroll
    for (int i = 0; i < 7; ++i) {
      int hr = gh + i; if (hr >= H_) hr -= H_;
      const float* drow = dptr + hr * W_;
#pragma unroll
      for (int j = 0; j < 7; ++j) {
        int wc = gw + j; if (wc >= W_) wc -= W_;
        const float l = drow[wc] + rpb[head * KK_ + i * 7 + j];
        logit[i * 7 + j] = l;
        m = fmaxf(m, l);
      }
    }
    float s = 0.f;
#pragma unroll
    for (int o = 0; o < KK_; ++o) {
      const float e = __expf(logit[o] - m);
      s += e;
      at[o * 256 + tid] = e;
    }
    rsum[tid] = 1.0f / s;
  }
  __syncthreads();

  const int c4  = tid & 7;
  const int seg = tid >> 3;
  const int r   = seg >> 1;
  const int sx  = (seg & 1) * 8;
  const int gh  = r0 + r;
  const int pxb = r * 16 + sx;
  const _Float16* vb = vbuf + (size_t)(b * NH_ + head) * HW_ * HD_ + c4 * 4;

  float4 acc[8];
#pragma unroll
  for (int xx = 0; xx < 8; ++xx) acc[xx] = make_float4(0.f, 0.f, 0.f, 0.f);

  for (int i = 0; i < 7; ++i) {
    int hr = gh + i; if (hr >= H_) hr -= H_;
    float4 win[14];
#pragma unroll
    for (int t = 0; t < 14; ++t) {
      int wc = w0 + sx + t; if (wc >= W_) wc -= W_;
      const halfx4 hv = *(const halfx4*)(vb + ((size_t)hr * W_ + wc) * HD_);
      win[t] = make_float4((float)hv[0], (float)hv[1], (float)hv[2], (float)hv[3]);
    }
#pragma unroll
    for (int j = 0; j < 7; ++j) {
      const float* arow = at + (i * 7 + j) * 256 + pxb;
      const float4 a0 = *(const float4*)arow;
      const float4 a1 = *(const float4*)(arow + 4);
      const float aw[8] = {a0.x, a0.y, a0.z, a0.w, a1.x, a1.y, a1.z, a1.w};
#pragma unroll
      for (int xx = 0; xx < 8; ++xx) {
        acc[xx].x = fmaf(aw[xx], win[xx + j].x, acc[xx].x);
        acc[xx].y = fmaf(aw[xx], win[xx + j].y, acc[xx].y);
        acc[xx].z = fmaf(aw[xx], win[xx + j].z, acc[xx].z);
        acc[xx].w = fmaf(aw[xx], win[xx + j].w, acc[xx].w);
      }
    }
  }

  // out: (B,HW,C) fp16, c = head*32 + c4*4 .. +3 (8B aligned)
  const size_t obase =
      ((size_t)b * HW_ + (size_t)gh * W_ + (w0 + sx)) * C_ + head * HD_ + c4 * 4;
#pragma unroll
  for (int xx = 0; xx < 8; ++xx) {
    const float rs = rsum[pxb + xx];
    halfx4 hv;
    hv[0] = (_Float16)(acc[xx].x * rs);
    hv[1] = (_Float16)(acc[xx].y * rs);
    hv[2] = (_Float16)(acc[xx].z * rs);
    hv[3] = (_Float16)(acc[xx].w * rs);
    *(halfx4*)(aof + obase + (size_t)xx * C_) = hv;
  }
}

// ---------------- K3: proj via fp16 MFMA + NHWC -> NCHW -------------------
// Block = 64 px, 4 waves; wave w -> oc in [w*32, w*32+32). No LDS, no barrier.
// R6: single fp16 ao plane + fp16 weights + mfma_f32_16x16x32_f16 (measured
// win vs bf16 hi/lo split, keep).
__global__ __launch_bounds__(256, 2) void k_proj(
    const _Float16* __restrict__ aof, const _Float16* __restrict__ pwf,
    const float* __restrict__ pb, float* __restrict__ out)
{
  const int tid = threadIdx.x;
  const int b   = blockIdx.x / 196;
  const int hw0 = (blockIdx.x % 196) * 64;
  const int w    = __builtin_amdgcn_readfirstlane(tid >> 6);
  const int l    = tid & 63;
  const int m16  = l & 15;
  const int quad = l >> 4;

  floatx4 acc[2][4];
#pragma unroll
  for (int t = 0; t < 2; ++t)
#pragma unroll
    for (int p = 0; p < 4; ++p) acc[t][p] = (floatx4){0.f, 0.f, 0.f, 0.f};

  const size_t pxbase = (size_t)b * HW_ + hw0;

  for (int ks = 0; ks < 4; ++ks) {
    half8 bb[4];
#pragma unroll
    for (int p = 0; p < 4; ++p) {
      const size_t off = (pxbase + p * 16 + m16) * C_ + ks * 32 + quad * 8;
      bb[p] = *(const half8*)(aof + off);
    }
#pragma unroll
    for (int t = 0; t < 2; ++t) {
      const size_t woff = (size_t)(w * 32 + t * 16 + m16) * C_ + ks * 32 + quad * 8;
      const half8 wa = *(const half8*)(pwf + woff);
#pragma unroll
      for (int p = 0; p < 4; ++p) {
        acc[t][p] = __builtin_amdgcn_mfma_f32_16x16x32_f16(wa, bb[p], acc[t][p], 0, 0, 0);
      }
    }
  }

#pragma unroll
  for (int t = 0; t < 2; ++t) {
    float bias[4];
#pragma unroll
    for (int r = 0; r < 4; ++r) bias[r] = pb[w * 32 + t * 16 + quad * 4 + r];
#pragma unroll
    for (int p = 0; p < 4; ++p) {
#pragma unroll
      for (int r = 0; r < 4; ++r) {
        const int oc = w * 32 + t * 16 + quad * 4 + r;
        out[(size_t)b * C_ * HW_ + (size_t)oc * HW_ + hw0 + p * 16 + m16] =
            acc[t][p][r] + bias[r];
      }
    }
  }
}

extern "C" void kernel_launch(void* const* d_in, const int* in_sizes, int n_in,
                              void* d_out, int out_size, void* d_ws, size_t ws_size,
                              hipStream_t stream) {
  const float* x   = (const float*)d_in[0];
  const float* qw  = (const float*)d_in[1];
  const float* qb  = (const float*)d_in[2];
  const float* rpb = (const float*)d_in[3];
  const float* pw  = (const float*)d_in[4];
  const float* pb  = (const float*)d_in[5];
  float* out = (float*)d_out;

  _Float16* vbuf = (_Float16*)d_ws;                    // N*C fp16 (25.7 MB)
  float* dotb = (float*)(vbuf + (size_t)N_ * C_);      // N*NH fp32 (1.6 MB)
  _Float16* aof = (_Float16*)(dotb + (size_t)N_ * NH_); // N*C fp16 (25.7 MB)
  _Float16* qwf = aof + (size_t)N_ * C_;               // 384*128 fp16
  _Float16* pwf = qwf + 384 * C_;                      // 128*128 fp16

  hipLaunchKernelGGL(k_wt,   dim3(192), dim3(256), 0, stream, qw, pw, qwf, pwf);
  hipLaunchKernelGGL(k_qkv,  dim3(N_ / 64), dim3(256), 0, stream, x, qwf, qb, vbuf, dotb);
  hipLaunchKernelGGL(k_attn, dim3(NH_ * B_ * 49), dim3(256), 0, stream, vbuf, dotb, rpb, aof);
  hipLaunchKernelGGL(k_proj, dim3(N_ / 64), dim3(256), 0, stream, aof, pwf, pb, out);
}